// Round 3
// baseline (911.505 us; speedup 1.0000x reference)
//
#include <hip/hip_runtime.h>

// BinarizeLayer forward — wave-independent version (no mid-kernel barrier):
//   Each 64-lane wave owns 64 rows end-to-end: load -> compute -> store.
//   Cross-lane LDS dependencies are wave-internal; a ds op retires (lgkmcnt)
//   only after commit to LDS, so `s_waitcnt lgkmcnt(0)` + compiler memory
//   clobber replaces __syncthreads for wave-private tiles. This lets one
//   wave's phase-3 stores overlap another wave's phase-2 compute (the old
//   block-wide barrier forced compute-then-store lockstep: VALU and the HBM
//   write pipe alternated idle instead of overlapping).
//   Loss: per-wave partials -> d_ws (8192 doubles, no atomics); runtime
//   fallback to block-reduced 2048 partials if ws_size < 64 KB.
//   Numerics of soft_argmax_loss kept bit-identical to the verified kernel.
//   NOTE: nontemporal store needs a clang ext_vector pointer — HIP's float4
//   (HIP_vector_type class) is rejected by __builtin_nontemporal_store.

constexpr int kB      = 524288;
constexpr int kF      = 16;
constexpr int kK1     = 16;
constexpr int kK2     = 8;
constexpr int kRowIn  = 32;    // DISC + F
constexpr int kRowOut = 400;   // DISC + F*K1 + F*K2
constexpr float kEps  = 0.001f;
constexpr int kTPB    = 256;   // threads per block == rows per block
constexpr int kGrid   = kB / kTPB;     // 2048 blocks
constexpr int kC4     = kRowOut / 4;   // 100 float4 chunks per row
constexpr int kXStride = 33;   // LDS row stride in floats (conflict-free)
constexpr int kWPB    = kTPB / 64;     // waves per block (4)

typedef float f32x4 __attribute__((ext_vector_type(4)));   // clang-native vec4

template <int K>
__device__ __forceinline__ int soft_argmax_loss(const float* __restrict__ dd,
                                                double& lacc)
{
#pragma clang fp contract(off)
    // ---- loss term: sum_k d * softmax(-d). Fast exp: output is threshold-checked.
    float se = 0.f, sde = 0.f;
#pragma unroll
    for (int k = 0; k < K; ++k) {
        float e = __expf(-dd[k]);
        se += e; sde += dd[k] * e;
    }
    lacc += (double)(sde / se);

    // ---- argmax(softmax(-100*d)) fast path: first-occurrence argmax of z ----
    float z[K];
#pragma unroll
    for (int k = 0; k < K; ++k) z[k] = -100.0f * dd[k];
    float m = z[0]; int kmax = 0;
#pragma unroll
    for (int k = 1; k < K; ++k) {
        if (z[k] > m) { m = z[k]; kmax = k; }
    }

    // softmax is a monotone-nondecreasing transform of z, so argmax can only
    // move to an EARLIER index j<kmax whose p_j rounds equal to p_kmax. That
    // needs exp(z_j-m) to round within ~1 ulp of exp(0)=1, i.e. z_j-m >= ~-1.2e-7.
    // (For large |m|, distinct z differ by >> that, so only exact ties pass.)
    bool cand = false;
#pragma unroll
    for (int k = 0; k < K; ++k)
        cand |= (k < kmax) & (z[k] >= m - 2.4e-7f);
    if (cand) {
        // exact replication of the fp32 reference: accurate expf, ordered sum,
        // IEEE divides, strict-> first-occurrence scan.
        float e2[K]; float ss = 0.f;
        for (int k = 0; k < K; ++k) { e2[k] = expf(z[k] - m); ss += e2[k]; }
        int km = 0; float pmax = e2[0] / ss;
        for (int k = 1; k < K; ++k) {
            float p = e2[k] / ss;
            if (p > pmax) { pmax = p; km = k; }
        }
        kmax = km;
    }
    return kmax;
}

__global__ __launch_bounds__(kTPB) void binlayer_main(
    const float* __restrict__ x,
    const float* __restrict__ interval,
    const float* __restrict__ interval2,
    const float* __restrict__ i_min,
    float* __restrict__ out,
    double* __restrict__ partial,
    int perwave)
{
#pragma clang fp contract(off)
    __shared__ float sC1[kF][kK1];
    __shared__ float sC2[kF][kK2];
    __shared__ float sX[kTPB * kXStride];
    __shared__ unsigned char sIdx[kTPB * kF];
    __shared__ double sL[kWPB];

    const int tid = threadIdx.x;
    const int w   = tid >> 6;     // wave id within block
    const int l   = tid & 63;     // lane id

    // centers: i_min + fp32 cumsum of max(interval, eps), in k order
    if (tid < kF) {
        const float base = i_min[tid];
        float run = 0.f;
        for (int k = 0; k < kK1; ++k) {
            run += fmaxf(interval[tid * kK1 + k], kEps);
            sC1[tid][k] = base + run;
        }
        run = 0.f;
        for (int k = 0; k < kK2; ++k) {
            run += fmaxf(interval2[tid * kK2 + k], kEps);
            sC2[tid][k] = base + run;
        }
    }
    __syncthreads();   // the ONLY block-wide barrier: sC visibility; waves
                       // desynchronize freely afterwards.

    const long long rowBase = (long long)blockIdx.x * kTPB;
    const int R0 = w * 64;        // this wave's first row in the block tile

    // -------- phase 1 (per-wave): 64 rows x 32 f32 -> LDS, coalesced --------
    const f32x4* __restrict__ xin4 = (const f32x4*)(x + (rowBase + R0) * kRowIn);
#pragma unroll
    for (int i = 0; i < 8; ++i) {
        int flat = i * 64 + l;                 // 0..511 float4s of this wave's tile
        f32x4 v = xin4[flat];
        int r = R0 + (flat >> 3), c4 = flat & 7;
        float* p = &sX[r * kXStride + c4 * 4];
        p[0] = v.x; p[1] = v.y; p[2] = v.z; p[3] = v.w;
    }
    // wave-local fence: ds_write retires only after commit; completed writes
    // are visible to all lanes. Memory clobber pins compiler ordering.
    asm volatile("s_waitcnt lgkmcnt(0)" ::: "memory");

    // -------- phase 2: one row per thread (row == tid) --------
    double lacc = 0.0;
    const float* __restrict__ myc = &sX[tid * kXStride + 16];

#pragma unroll 1
    for (int f = 0; f < kF; ++f) {
        const float c = myc[f];

        float dd1[kK1];
#pragma unroll
        for (int k = 0; k < kK1; ++k) { float t = c - sC1[f][k]; dd1[k] = t * t; }
        int k1 = soft_argmax_loss<kK1>(dd1, lacc);

        float dd2[kK2];
#pragma unroll
        for (int k = 0; k < kK2; ++k) { float t = c - sC2[f][k]; dd2[k] = t * t; }
        int k2 = soft_argmax_loss<kK2>(dd2, lacc);

        sIdx[tid * kF + f] = (unsigned char)(k1 | (k2 << 4));
    }
    // wave-local fence for sIdx (written by this wave, read cross-lane below)
    asm volatile("s_waitcnt lgkmcnt(0)" ::: "memory");

    // loss: wave shuffle-reduce; per-wave partial store (no cross-wave sync)
#pragma unroll
    for (int off = 32; off > 0; off >>= 1) lacc += __shfl_down(lacc, off);
    if (perwave) {
        if (l == 0) partial[(long long)blockIdx.x * kWPB + w] = lacc;
    } else {
        // fallback when ws too small for per-wave partials (needs one barrier)
        if (l == 0) sL[w] = lacc;
        __syncthreads();
        if (tid == 0) partial[blockIdx.x] = sL[0] + sL[1] + sL[2] + sL[3];
    }

    // -------- phase 3 (per-wave): 64 rows x 100 float4, fully coalesced ------
    f32x4* __restrict__ o4 = (f32x4*)(out + (rowBase + R0) * kRowOut);
#pragma unroll 1
    for (int i = 0; i < kC4; ++i) {                  // 100 iters
        unsigned idx = (unsigned)(i * 64 + l);       // 0..6399
        unsigned r = idx / 100u;                     // row within wave tile
        unsigned c = idx - r * 100u;                 // float4 chunk in row
        unsigned rr = (unsigned)R0 + r;
        f32x4 o;
        if (c < 4u) {
            const float* p = &sX[rr * kXStride + c * 4u];
            o.x = p[0]; o.y = p[1]; o.z = p[2]; o.w = p[3];
        } else if (c < 68u) {
            unsigned u = c - 4u, f = u >> 2, q = (u & 3u) * 4u;
            unsigned k = sIdx[rr * kF + f] & 15u;
            o.x = (k == q + 0u) ? 1.f : 0.f;
            o.y = (k == q + 1u) ? 1.f : 0.f;
            o.z = (k == q + 2u) ? 1.f : 0.f;
            o.w = (k == q + 3u) ? 1.f : 0.f;
        } else {
            unsigned u = c - 68u, f = u >> 1, q = (u & 1u) * 4u;
            unsigned k = (unsigned)(sIdx[rr * kF + f]) >> 4;
            o.x = (k == q + 0u) ? 1.f : 0.f;
            o.y = (k == q + 1u) ? 1.f : 0.f;
            o.z = (k == q + 2u) ? 1.f : 0.f;
            o.w = (k == q + 3u) ? 1.f : 0.f;
        }
        // streaming store: out is write-once, never re-read -> keep it out of L2
        __builtin_nontemporal_store(o, &o4[idx]);
    }
}

__global__ __launch_bounds__(256) void binlayer_finalize(
    const double* __restrict__ partial,
    float* __restrict__ out,
    int n)
{
    __shared__ double sL[4];
    const int tid = threadIdx.x;
    double s = 0.0;
    for (int i = tid; i < n; i += 256)
        s += partial[i];
#pragma unroll
    for (int off = 32; off > 0; off >>= 1) s += __shfl_down(s, off);
    if ((tid & 63) == 0) sL[tid >> 6] = s;
    __syncthreads();
    if (tid == 0)
        out[(long long)kB * kRowOut] =
            (float)((sL[0] + sL[1] + sL[2] + sL[3]) * (1.0 / (double)kB));
}

extern "C" void kernel_launch(void* const* d_in, const int* in_sizes, int n_in,
                              void* d_out, int out_size, void* d_ws, size_t ws_size,
                              hipStream_t stream)
{
    const float* x    = (const float*)d_in[0];
    const float* itv1 = (const float*)d_in[1];
    const float* itv2 = (const float*)d_in[2];
    const float* imin = (const float*)d_in[3];
    float* out = (float*)d_out;
    double* partial = (double*)d_ws;

    const int perwave = (ws_size >= (size_t)kGrid * kWPB * sizeof(double)) ? 1 : 0;
    const int nPartial = perwave ? kGrid * kWPB : kGrid;   // 8192 or 2048 doubles

    binlayer_main<<<kGrid, kTPB, 0, stream>>>(x, itv1, itv2, imin, out, partial, perwave);
    binlayer_finalize<<<1, 256, 0, stream>>>(partial, out, nPartial);
}